// Round 9
// baseline (255.458 us; speedup 1.0000x reference)
//
#include <hip/hip_runtime.h>
#include <cstdint>

// FCOS detection post-process for MI355X.
// Pipeline: score/box decode -> per-image exact top-1000 (bitonic chunk sort +
// tree merge) -> suppression bitmask -> span-based greedy NMS scan -> outputs.

typedef unsigned long long ull;

#define BATCH 16
#define NLOC 17064      // total FPN locations per image
#define NPAD 18432      // padded to 9 * 2048
#define NCHUNK 9
#define CHUNK 2048
#define TOPK 1000
#define TOPKP 1024
#define NCLS 80
#define SCORE_THR 0.05f
#define IOU_THR 0.6f

struct Ptrs { const float* cls[5]; const float* reg[5]; const float* ctr[5]; };

// ---------------------------------------------------------------- kernel 1 --
// One thread per (image, location): argmax over 80 class logits (sigmoid is
// monotonic), score = sqrt(sig(cls_max)*sig(ctr)), box decode, pack sort key.
// Key = (score_bits << 32) | (0xFFFFFFFF - n): descending sort == lax.top_k
// order (ties -> smaller index first). Padding locations get key 0.
__global__ __launch_bounds__(256) void score_kernel(Ptrs p, ull* __restrict__ keys,
                                                    int* __restrict__ labels,
                                                    float* __restrict__ boxes) {
  int idx = blockIdx.x * 256 + threadIdx.x;
  if (idx >= BATCH * NPAD) return;
  int b = idx / NPAD, n = idx - b * NPAD;
  if (n >= NLOC) { keys[idx] = 0ull; return; }

  int lvl, off, lw, st, H;
  if (n < 12800)      { lvl=0; off=0;     lw=7; st=8;   H=100; }
  else if (n < 16000) { lvl=1; off=12800; lw=6; st=16;  H=50;  }
  else if (n < 16800) { lvl=2; off=16000; lw=5; st=32;  H=25;  }
  else if (n < 17008) { lvl=3; off=16800; lw=4; st=64;  H=13;  }
  else                { lvl=4; off=17008; lw=3; st=128; H=7;   }
  int hw = n - off;
  int w = hw & ((1 << lw) - 1), h = hw >> lw;
  int HW = H << lw;
  float fs = (float)st, half = fs * 0.5f;
  float x = (float)w * fs + half, y = (float)h * fs + half;

  // coalesced across threads (consecutive hw) for each class c
  const float* cb = p.cls[lvl] + (size_t)b * NCLS * HW + hw;
  float best = cb[0]; int bi = 0;
  for (int c = 1; c < NCLS; ++c) {
    float v = cb[(size_t)c * HW];
    if (v > best) { best = v; bi = c; }   // strict > keeps first max (jnp.argmax)
  }
  const float* rb = p.reg[lvl] + (size_t)b * 4 * HW + hw;
  float r0 = rb[0], r1 = rb[HW], r2 = rb[2 * (size_t)HW], r3 = rb[3 * (size_t)HW];
  float ct = p.ctr[lvl][(size_t)b * HW + hw];

  float pcls = 1.f / (1.f + expf(-best));
  float pctr = 1.f / (1.f + expf(-ct));
  float score = sqrtf(pcls * pctr);   // (0,1), always positive -> monotonic bits

  keys[idx] = ((ull)__float_as_uint(score) << 32) | (ull)(0xFFFFFFFFu - (unsigned)n);
  labels[(size_t)b * NLOC + n] = bi + 1;
  float* bx = boxes + ((size_t)b * NLOC + n) * 4;
  bx[0] = x - r0; bx[1] = y - r1; bx[2] = x + r2; bx[3] = y + r3;
}

// ---------------------------------------------------------------- kernel 2 --
// Bitonic sort of one 2048 chunk in LDS (descending); emit top-1024.
__global__ __launch_bounds__(512) void chunk_sort_kernel(const ull* __restrict__ keys,
                                                         ull* __restrict__ runs) {
  __shared__ ull s[CHUNK];
  int b = blockIdx.x / NCHUNK, c = blockIdx.x % NCHUNK;
  const ull* src = keys + (size_t)b * NPAD + (size_t)c * CHUNK;
  for (int i = threadIdx.x; i < CHUNK; i += 512) s[i] = src[i];
  __syncthreads();
  for (int k = 2; k <= CHUNK; k <<= 1) {
    for (int j = k >> 1; j > 0; j >>= 1) {
      for (int t = threadIdx.x; t < CHUNK / 2; t += 512) {
        int i = ((t & ~(j - 1)) << 1) | (t & (j - 1));
        int ixj = i | j;
        bool desc = (i & k) == 0;
        ull a = s[i], bb = s[ixj];
        bool sw = desc ? (a < bb) : (a > bb);
        if (sw) { s[i] = bb; s[ixj] = a; }
      }
      __syncthreads();
    }
  }
  ull* dst = runs + ((size_t)b * NCHUNK + c) * TOPKP;
  for (int i = threadIdx.x; i < TOPKP; i += 512) dst[i] = s[i];
}

// ---------------------------------------------------------------- kernel 3 --
// One tree-merge level: block (b,p) merges src runs (2p,2p+1) -> dst run p,
// keeping only the top-1024 (first bitonic-merge pass + descending clean of
// the top half). Carry block copies the odd run through. Ping-pong buffers.
__global__ __launch_bounds__(512) void merge_level_kernel(const ull* __restrict__ src,
    ull* __restrict__ dst, int npairs, int carry, int srcRPI, int dstRPI) {
  int per = npairs + carry;
  int b = blockIdx.x / per, p = blockIdx.x % per;
  const ull* sb = src + (size_t)b * srcRPI * TOPKP;
  ull* db = dst + (size_t)b * dstRPI * TOPKP;
  int tid = threadIdx.x;
  if (p >= npairs) {   // carry: copy last odd run through
    for (int i = tid; i < TOPKP; i += 512)
      db[(size_t)p * TOPKP + i] = sb[(size_t)(2 * npairs) * TOPKP + i];
    return;
  }
  __shared__ ull m[TOPKP];
  const ull* A = sb + (size_t)(2 * p) * TOPKP;
  const ull* B = sb + (size_t)(2 * p + 1) * TOPKP;
  // pass j=1024 of the 2048 bitonic merge: top half = max(A[i], B[1023-i])
  for (int i = tid; i < TOPKP; i += 512) {
    ull a = A[i], c = B[TOPKP - 1 - i];
    m[i] = a > c ? a : c;
  }
  __syncthreads();
  // descending bitonic clean of the (bitonic) top half
  for (int j = TOPKP / 2; j > 0; j >>= 1) {
    for (int t = tid; t < TOPKP / 2; t += 512) {
      int i = ((t & ~(j - 1)) << 1) | (t & (j - 1));
      int ixj = i | j;
      ull a = m[i], c = m[ixj];
      if (a < c) { m[i] = c; m[ixj] = a; }
    }
    __syncthreads();
  }
  for (int i = tid; i < TOPKP; i += 512) db[(size_t)p * TOPKP + i] = m[i];
}

// ---------------------------------------------------------------- kernel 4 --
// Decode keys, gather label/box, write output boxes, coord_max reduction
// (exact: max is order-independent), class-offset boxes, valid-bit words.
__global__ __launch_bounds__(256) void gather_kernel(const ull* __restrict__ topkeys,
    const int* __restrict__ labels, const float* __restrict__ boxes,
    float* __restrict__ topS, int* __restrict__ topL, float* __restrict__ topOB,
    ull* __restrict__ validWords, float* __restrict__ outBoxes) {
  __shared__ float red[256];
  __shared__ float s_cmax;
  int b = blockIdx.x, tid = threadIdx.x;
  float lmax = 0.f;   // reference maxes over where(valid, bx, 0) -> zeros included
  for (int k = tid; k < TOPKP; k += 256) {
    ull key = topkeys[(size_t)b * TOPKP + k];
    float sc = 0.f; int lb = 0;
    float b0 = 0.f, b1 = 0.f, b2 = 0.f, b3 = 0.f;
    bool inR = (k < TOPK);
    if (inR) {
      sc = __uint_as_float((unsigned)(key >> 32));
      unsigned n = 0xFFFFFFFFu - (unsigned)(key & 0xFFFFFFFFull);
      lb = labels[(size_t)b * NLOC + n];
      const float* bp = boxes + ((size_t)b * NLOC + n) * 4;
      b0 = bp[0]; b1 = bp[1]; b2 = bp[2]; b3 = bp[3];
      float* ob = outBoxes + ((size_t)b * TOPK + k) * 4;
      ob[0] = b0; ob[1] = b1; ob[2] = b2; ob[3] = b3;   // boxes output: all 1000
    }
    topS[(size_t)b * TOPKP + k] = sc;
    topL[(size_t)b * TOPKP + k] = lb;
    float* tb = topOB + ((size_t)b * TOPKP + k) * 4;
    tb[0] = b0; tb[1] = b1; tb[2] = b2; tb[3] = b3;
    bool valid = inR && (sc > SCORE_THR);
    if (valid) lmax = fmaxf(lmax, fmaxf(fmaxf(b0, b1), fmaxf(b2, b3)));
    ull vb = __ballot(valid ? 1 : 0);
    if ((tid & 63) == 0) validWords[b * 16 + (k >> 6)] = vb;
  }
  red[tid] = lmax;
  __syncthreads();
  for (int sft = 128; sft > 0; sft >>= 1) {
    if (tid < sft) red[tid] = fmaxf(red[tid], red[tid + sft]);
    __syncthreads();
  }
  if (tid == 0) s_cmax = red[0];
  __syncthreads();
  float offb = s_cmax + 1.0f;
  for (int k = tid; k < TOPKP; k += 256) {
    float off = (float)topL[(size_t)b * TOPKP + k] * offb;   // class-offset trick
    float* tb = topOB + ((size_t)b * TOPKP + k) * 4;
    tb[0] += off; tb[1] += off; tb[2] += off; tb[3] += off;
  }
}

// ---------------------------------------------------------------- kernel 5 --
// Suppression bitmask: block (b,i), thread j: bit = (j>i) & (iou(i,j) > thr).
// 16 uint64 words per row via per-wave ballot. Row stride = 16 words; rows
// stored at (b*TOPKP + i). FP op order mirrors reference.
__global__ __launch_bounds__(1024) void sup_kernel(const float* __restrict__ topOB,
                                                   ull* __restrict__ sup) {
  int bid = blockIdx.x;
  int b = bid / TOPK, i = bid - b * TOPK;
  int j = threadIdx.x;
  const float4* OB = (const float4*)topOB + (size_t)b * TOPKP;
  float4 A = OB[i];
  float aw = fmaxf(A.z - A.x, 0.f), ah = fmaxf(A.w - A.y, 0.f);
  float areaA = aw * ah;
  bool bit = false;
  if (j > i && j < TOPK) {
    float4 Bx = OB[j];
    float bw = fmaxf(Bx.z - Bx.x, 0.f), bh = fmaxf(Bx.w - Bx.y, 0.f);
    float areaB = bw * bh;
    float ix1 = fmaxf(A.x, Bx.x), iy1 = fmaxf(A.y, Bx.y);
    float ix2 = fminf(A.z, Bx.z), iy2 = fminf(A.w, Bx.w);
    float inter = fmaxf(ix2 - ix1, 0.f) * fmaxf(iy2 - iy1, 0.f);
    float uni = areaA + areaB - inter;
    float iou = inter / fmaxf(uni, 1e-9f);
    bit = iou > IOU_THR;
  }
  ull m = __ballot(bit ? 1 : 0);
  if ((j & 63) == 0) sup[((size_t)b * TOPKP + i) * 16 + (j >> 6)] = m;
}

// ---------------------------------------------------------------- kernel 6 --
// Span-based greedy scan, 1 wave per image. Lanes 0..15 own removed word lane.
// Per span w (64 candidates): lane k holds the DIAG word (row w*64+k, word w).
// The 64-step serial scan runs as a UNIFORM SCALAR chain: alive mask M lives
// in SGPRs; step K reads lane K's diag via readlane with CONSTANT index (pure
// register op, no DS, no waits -- R7/R8 showed shfl-in-chain pays ~40cyc DS
// latency per step that the compiler re-sinks into the chain regardless of
// source-level batching). Phase B: va bank (lane = word lane&15 of rows
// (lane>>4)+4t) OR-ed under uniform kept-mask km + 2 shfl_xor folds. Both
// the diag word and the va bank are double-buffered across spans.
__global__ __launch_bounds__(64) void nms_scan_kernel(const ull* __restrict__ sup,
    const ull* __restrict__ validWords, const float* __restrict__ topS,
    const int* __restrict__ topL, float* __restrict__ out) {
  int b = blockIdx.x, lane = threadIdx.x;
  const ull* S = sup + (size_t)b * TOPKP * 16;
  int lg = lane >> 4;    // lane group -> row offset mod 4
  int wd = lane & 15;    // word index owned by this lane
  ull rm = 0xFFFFFFFFFFFFFFFFull;
  if (lane < 16) rm = ~validWords[b * 16 + lane];   // removed = ~valid initially

  ull va0,va1,va2,va3,va4,va5,va6,va7,va8,va9,va10,va11,va12,va13,va14,va15;
  ull vb0,vb1,vb2,vb3,vb4,vb5,vb6,vb7,vb8,vb9,vb10,vb11,vb12,vb13,vb14,vb15;
  ull dga, dgb;

  // load bank PFX with span W's sub-block: PFX#t = row(W*64 + lg + 4t)[wd]
#define LOADS(PFX, W) { const ull* Bp = S + ((size_t)(W) * 64 + lg) * 16 + wd; \
    PFX##0 = Bp[0];    PFX##1 = Bp[64];   PFX##2 = Bp[128];  PFX##3 = Bp[192]; \
    PFX##4 = Bp[256];  PFX##5 = Bp[320];  PFX##6 = Bp[384];  PFX##7 = Bp[448]; \
    PFX##8 = Bp[512];  PFX##9 = Bp[576];  PFX##10 = Bp[640]; PFX##11 = Bp[704];\
    PFX##12 = Bp[768]; PFX##13 = Bp[832]; PFX##14 = Bp[896]; PFX##15 = Bp[960];}
  // diag word for span W: lane k <- row(W*64+k) word W
#define DIAG(DST, W) { DST = S[((size_t)(W) * 64 + lane) * 16 + (W)]; }
  // one scalar chain step (K constant): take = bit K of M; M &= ~(d_K & take)
#define CS(K) { unsigned rl = __builtin_amdgcn_readlane(dlo, (K));             \
    unsigned rh = __builtin_amdgcn_readlane(dhi, (K));                         \
    ull take = (M >> (K)) & 1ull; ull msk = 0ull - take;                       \
    M &= ~((((ull)rh << 32) | (ull)rl) & msk); km |= take << (K); }
#define CS8(B) CS((B)+0) CS((B)+1) CS((B)+2) CS((B)+3) CS((B)+4) CS((B)+5)     \
    CS((B)+6) CS((B)+7)
#define PB(PFX, T) { ull bit = (km >> (4 * (T) + lg)) & 1ull;                  \
    accB |= PFX##T & (0ull - bit); }
#define SPAN_BODY(PFX, DG, W) { int w_ = (W);                                  \
    unsigned dlo = (unsigned)(DG), dhi = (unsigned)((DG) >> 32);               \
    unsigned mlo = __builtin_amdgcn_readlane((unsigned)rm, w_);                \
    unsigned mhi = __builtin_amdgcn_readlane((unsigned)(rm >> 32), w_);        \
    ull M = ~(((ull)mhi << 32) | (ull)mlo);                                    \
    ull km = 0;                                                                \
    CS8(0) CS8(8) CS8(16) CS8(24) CS8(32) CS8(40) CS8(48) CS8(56)              \
    ull accB = 0;                                                              \
    PB(PFX,0) PB(PFX,1) PB(PFX,2) PB(PFX,3) PB(PFX,4) PB(PFX,5) PB(PFX,6)      \
    PB(PFX,7) PB(PFX,8) PB(PFX,9) PB(PFX,10) PB(PFX,11) PB(PFX,12) PB(PFX,13)  \
    PB(PFX,14) PB(PFX,15)                                                      \
    accB |= __shfl_xor(accB, 16);                                              \
    accB |= __shfl_xor(accB, 32);                                              \
    rm |= accB; }

  LOADS(va, 0)
  DIAG(dga, 0)
  for (int w = 0; w < 16; w += 2) {
    int wn1 = (w + 1 < 16) ? w + 1 : 15;
    LOADS(vb, wn1)            // in flight during va's chain
    DIAG(dgb, wn1)
    SPAN_BODY(va, dga, w)
    int wn2 = (w + 2 < 16) ? w + 2 : 15;
    LOADS(va, wn2)            // in flight during vb's chain
    DIAG(dga, wn2)
    SPAN_BODY(vb, dgb, w + 1)
  }
#undef SPAN_BODY
#undef PB
#undef CS8
#undef CS
#undef DIAG
#undef LOADS

  ull keep_na = ~rm;   // lanes 0..15: keep word lane (~rm subset of valid)
  const float* tS = topS + (size_t)b * TOPKP;
  const int*   tL = topL + (size_t)b * TOPKP;
  float* outS = out;                          // [16,1000]
  float* outL = out + BATCH * TOPK;           // [16,1000] labels as float
  float* outK = out + BATCH * TOPK * 6;       // after boxes block
  for (int t = 0; t < 16; ++t) {
    int j = t * 64 + lane;
    ull kw = __shfl(keep_na, t);
    if (j < TOPK) {
      bool kp = (kw >> lane) & 1ull;
      outS[(size_t)b * TOPK + j] = kp ? tS[j] : 0.f;
      outL[(size_t)b * TOPK + j] = kp ? (float)tL[j] : 0.f;
      outK[(size_t)b * TOPK + j] = kp ? 1.f : 0.f;
    }
  }
}

// -------------------------------------------------------------------- host --
extern "C" void kernel_launch(void* const* d_in, const int* in_sizes, int n_in,
                              void* d_out, int out_size, void* d_ws, size_t ws_size,
                              hipStream_t stream) {
  Ptrs p;
  for (int l = 0; l < 5; ++l) {
    p.cls[l] = (const float*)d_in[l];
    p.reg[l] = (const float*)d_in[5 + l];
    p.ctr[l] = (const float*)d_in[10 + l];
  }
  char* ws = (char*)d_ws;
  size_t o = 0;
  auto alloc = [&](size_t bytes) -> void* {
    void* r = ws + o; o += (bytes + 255) & ~(size_t)255; return r;
  };
  ull*   keys       = (ull*)  alloc((size_t)BATCH * NPAD * 8);
  int*   labels     = (int*)  alloc((size_t)BATCH * NLOC * 4);
  float* boxes      = (float*)alloc((size_t)BATCH * NLOC * 16);
  ull*   runs       = (ull*)  alloc((size_t)BATCH * NCHUNK * TOPKP * 8);
  ull*   runs2      = (ull*)  alloc((size_t)BATCH * NCHUNK * TOPKP * 8);
  ull*   topkeys    = (ull*)  alloc((size_t)BATCH * TOPKP * 8);
  float* topS       = (float*)alloc((size_t)BATCH * TOPKP * 4);
  int*   topL       = (int*)  alloc((size_t)BATCH * TOPKP * 4);
  float* topOB      = (float*)alloc((size_t)BATCH * TOPKP * 16);
  ull*   validWords = (ull*)  alloc((size_t)BATCH * 16 * 8);
  ull*   sup        = (ull*)  alloc((size_t)BATCH * TOPKP * 16 * 8);

  float* out = (float*)d_out;
  float* outBoxes = out + 2 * BATCH * TOPK;   // offset 32000

  hipLaunchKernelGGL(score_kernel, dim3((BATCH * NPAD + 255) / 256), dim3(256), 0, stream,
                     p, keys, labels, boxes);
  hipLaunchKernelGGL(chunk_sort_kernel, dim3(BATCH * NCHUNK), dim3(512), 0, stream,
                     keys, runs);
  // tree merge: 9 -> 5 -> 3 -> 2 -> 1 (ping-pong runs/runs2)
  hipLaunchKernelGGL(merge_level_kernel, dim3(BATCH * 5), dim3(512), 0, stream,
                     runs, runs2, 4, 1, NCHUNK, NCHUNK);
  hipLaunchKernelGGL(merge_level_kernel, dim3(BATCH * 3), dim3(512), 0, stream,
                     runs2, runs, 2, 1, NCHUNK, NCHUNK);
  hipLaunchKernelGGL(merge_level_kernel, dim3(BATCH * 2), dim3(512), 0, stream,
                     runs, runs2, 1, 1, NCHUNK, NCHUNK);
  hipLaunchKernelGGL(merge_level_kernel, dim3(BATCH * 1), dim3(512), 0, stream,
                     runs2, topkeys, 1, 0, NCHUNK, 1);
  hipLaunchKernelGGL(gather_kernel, dim3(BATCH), dim3(256), 0, stream,
                     topkeys, labels, boxes, topS, topL, topOB, validWords, outBoxes);
  hipLaunchKernelGGL(sup_kernel, dim3(BATCH * TOPK), dim3(1024), 0, stream,
                     topOB, sup);
  hipLaunchKernelGGL(nms_scan_kernel, dim3(BATCH), dim3(64), 0, stream,
                     sup, validWords, topS, topL, out);
}

// Round 10
// 254.366 us; speedup vs baseline: 1.0043x; 1.0043x over previous
//
#include <hip/hip_runtime.h>
#include <cstdint>

// FCOS detection post-process for MI355X.
// Pipeline: score/box decode -> per-image exact top-1000 (bitonic chunk sort +
// tree merge) -> suppression bitmask -> LDS-staged greedy NMS scan -> outputs.

typedef unsigned long long ull;

#define BATCH 16
#define NLOC 17064      // total FPN locations per image
#define NPAD 18432      // padded to 9 * 2048
#define NCHUNK 9
#define CHUNK 2048
#define TOPK 1000
#define TOPKP 1024
#define NCLS 80
#define SCORE_THR 0.05f
#define IOU_THR 0.6f

struct Ptrs { const float* cls[5]; const float* reg[5]; const float* ctr[5]; };

// ---------------------------------------------------------------- kernel 1 --
// One thread per (image, location): argmax over 80 class logits (sigmoid is
// monotonic), score = sqrt(sig(cls_max)*sig(ctr)), box decode, pack sort key.
// Key = (score_bits << 32) | (0xFFFFFFFF - n): descending sort == lax.top_k
// order (ties -> smaller index first). Padding locations get key 0.
__global__ __launch_bounds__(256) void score_kernel(Ptrs p, ull* __restrict__ keys,
                                                    int* __restrict__ labels,
                                                    float* __restrict__ boxes) {
  int idx = blockIdx.x * 256 + threadIdx.x;
  if (idx >= BATCH * NPAD) return;
  int b = idx / NPAD, n = idx - b * NPAD;
  if (n >= NLOC) { keys[idx] = 0ull; return; }

  int lvl, off, lw, st, H;
  if (n < 12800)      { lvl=0; off=0;     lw=7; st=8;   H=100; }
  else if (n < 16000) { lvl=1; off=12800; lw=6; st=16;  H=50;  }
  else if (n < 16800) { lvl=2; off=16000; lw=5; st=32;  H=25;  }
  else if (n < 17008) { lvl=3; off=16800; lw=4; st=64;  H=13;  }
  else                { lvl=4; off=17008; lw=3; st=128; H=7;   }
  int hw = n - off;
  int w = hw & ((1 << lw) - 1), h = hw >> lw;
  int HW = H << lw;
  float fs = (float)st, half = fs * 0.5f;
  float x = (float)w * fs + half, y = (float)h * fs + half;

  // coalesced across threads (consecutive hw) for each class c
  const float* cb = p.cls[lvl] + (size_t)b * NCLS * HW + hw;
  float best = cb[0]; int bi = 0;
  for (int c = 1; c < NCLS; ++c) {
    float v = cb[(size_t)c * HW];
    if (v > best) { best = v; bi = c; }   // strict > keeps first max (jnp.argmax)
  }
  const float* rb = p.reg[lvl] + (size_t)b * 4 * HW + hw;
  float r0 = rb[0], r1 = rb[HW], r2 = rb[2 * (size_t)HW], r3 = rb[3 * (size_t)HW];
  float ct = p.ctr[lvl][(size_t)b * HW + hw];

  float pcls = 1.f / (1.f + expf(-best));
  float pctr = 1.f / (1.f + expf(-ct));
  float score = sqrtf(pcls * pctr);   // (0,1), always positive -> monotonic bits

  keys[idx] = ((ull)__float_as_uint(score) << 32) | (ull)(0xFFFFFFFFu - (unsigned)n);
  labels[(size_t)b * NLOC + n] = bi + 1;
  float* bx = boxes + ((size_t)b * NLOC + n) * 4;
  bx[0] = x - r0; bx[1] = y - r1; bx[2] = x + r2; bx[3] = y + r3;
}

// ---------------------------------------------------------------- kernel 2 --
// Bitonic sort of one 2048 chunk in LDS (descending); emit top-1024.
__global__ __launch_bounds__(512) void chunk_sort_kernel(const ull* __restrict__ keys,
                                                         ull* __restrict__ runs) {
  __shared__ ull s[CHUNK];
  int b = blockIdx.x / NCHUNK, c = blockIdx.x % NCHUNK;
  const ull* src = keys + (size_t)b * NPAD + (size_t)c * CHUNK;
  for (int i = threadIdx.x; i < CHUNK; i += 512) s[i] = src[i];
  __syncthreads();
  for (int k = 2; k <= CHUNK; k <<= 1) {
    for (int j = k >> 1; j > 0; j >>= 1) {
      for (int t = threadIdx.x; t < CHUNK / 2; t += 512) {
        int i = ((t & ~(j - 1)) << 1) | (t & (j - 1));
        int ixj = i | j;
        bool desc = (i & k) == 0;
        ull a = s[i], bb = s[ixj];
        bool sw = desc ? (a < bb) : (a > bb);
        if (sw) { s[i] = bb; s[ixj] = a; }
      }
      __syncthreads();
    }
  }
  ull* dst = runs + ((size_t)b * NCHUNK + c) * TOPKP;
  for (int i = threadIdx.x; i < TOPKP; i += 512) dst[i] = s[i];
}

// ---------------------------------------------------------------- kernel 3 --
// One tree-merge level: block (b,p) merges src runs (2p,2p+1) -> dst run p,
// keeping only the top-1024 (first bitonic-merge pass + descending clean of
// the top half). Carry block copies the odd run through. Ping-pong buffers.
__global__ __launch_bounds__(512) void merge_level_kernel(const ull* __restrict__ src,
    ull* __restrict__ dst, int npairs, int carry, int srcRPI, int dstRPI) {
  int per = npairs + carry;
  int b = blockIdx.x / per, p = blockIdx.x % per;
  const ull* sb = src + (size_t)b * srcRPI * TOPKP;
  ull* db = dst + (size_t)b * dstRPI * TOPKP;
  int tid = threadIdx.x;
  if (p >= npairs) {   // carry: copy last odd run through
    for (int i = tid; i < TOPKP; i += 512)
      db[(size_t)p * TOPKP + i] = sb[(size_t)(2 * npairs) * TOPKP + i];
    return;
  }
  __shared__ ull m[TOPKP];
  const ull* A = sb + (size_t)(2 * p) * TOPKP;
  const ull* B = sb + (size_t)(2 * p + 1) * TOPKP;
  // pass j=1024 of the 2048 bitonic merge: top half = max(A[i], B[1023-i])
  for (int i = tid; i < TOPKP; i += 512) {
    ull a = A[i], c = B[TOPKP - 1 - i];
    m[i] = a > c ? a : c;
  }
  __syncthreads();
  // descending bitonic clean of the (bitonic) top half
  for (int j = TOPKP / 2; j > 0; j >>= 1) {
    for (int t = tid; t < TOPKP / 2; t += 512) {
      int i = ((t & ~(j - 1)) << 1) | (t & (j - 1));
      int ixj = i | j;
      ull a = m[i], c = m[ixj];
      if (a < c) { m[i] = c; m[ixj] = a; }
    }
    __syncthreads();
  }
  for (int i = tid; i < TOPKP; i += 512) db[(size_t)p * TOPKP + i] = m[i];
}

// ---------------------------------------------------------------- kernel 4 --
// Decode keys, gather label/box, write output boxes, coord_max reduction
// (exact: max is order-independent), class-offset boxes, valid-bit words.
__global__ __launch_bounds__(256) void gather_kernel(const ull* __restrict__ topkeys,
    const int* __restrict__ labels, const float* __restrict__ boxes,
    float* __restrict__ topS, int* __restrict__ topL, float* __restrict__ topOB,
    ull* __restrict__ validWords, float* __restrict__ outBoxes) {
  __shared__ float red[256];
  __shared__ float s_cmax;
  int b = blockIdx.x, tid = threadIdx.x;
  float lmax = 0.f;   // reference maxes over where(valid, bx, 0) -> zeros included
  for (int k = tid; k < TOPKP; k += 256) {
    ull key = topkeys[(size_t)b * TOPKP + k];
    float sc = 0.f; int lb = 0;
    float b0 = 0.f, b1 = 0.f, b2 = 0.f, b3 = 0.f;
    bool inR = (k < TOPK);
    if (inR) {
      sc = __uint_as_float((unsigned)(key >> 32));
      unsigned n = 0xFFFFFFFFu - (unsigned)(key & 0xFFFFFFFFull);
      lb = labels[(size_t)b * NLOC + n];
      const float* bp = boxes + ((size_t)b * NLOC + n) * 4;
      b0 = bp[0]; b1 = bp[1]; b2 = bp[2]; b3 = bp[3];
      float* ob = outBoxes + ((size_t)b * TOPK + k) * 4;
      ob[0] = b0; ob[1] = b1; ob[2] = b2; ob[3] = b3;   // boxes output: all 1000
    }
    topS[(size_t)b * TOPKP + k] = sc;
    topL[(size_t)b * TOPKP + k] = lb;
    float* tb = topOB + ((size_t)b * TOPKP + k) * 4;
    tb[0] = b0; tb[1] = b1; tb[2] = b2; tb[3] = b3;
    bool valid = inR && (sc > SCORE_THR);
    if (valid) lmax = fmaxf(lmax, fmaxf(fmaxf(b0, b1), fmaxf(b2, b3)));
    ull vb = __ballot(valid ? 1 : 0);
    if ((tid & 63) == 0) validWords[b * 16 + (k >> 6)] = vb;
  }
  red[tid] = lmax;
  __syncthreads();
  for (int sft = 128; sft > 0; sft >>= 1) {
    if (tid < sft) red[tid] = fmaxf(red[tid], red[tid + sft]);
    __syncthreads();
  }
  if (tid == 0) s_cmax = red[0];
  __syncthreads();
  float offb = s_cmax + 1.0f;
  for (int k = tid; k < TOPKP; k += 256) {
    float off = (float)topL[(size_t)b * TOPKP + k] * offb;   // class-offset trick
    float* tb = topOB + ((size_t)b * TOPKP + k) * 4;
    tb[0] += off; tb[1] += off; tb[2] += off; tb[3] += off;
  }
}

// ---------------------------------------------------------------- kernel 5 --
// Suppression bitmask: block (b,i), thread j: bit = (j>i) & (iou(i,j) > thr).
// 16 uint64 words per row via per-wave ballot. Row stride = 16 words; rows
// stored at (b*TOPKP + i). FP op order mirrors reference.
__global__ __launch_bounds__(1024) void sup_kernel(const float* __restrict__ topOB,
                                                   ull* __restrict__ sup) {
  int bid = blockIdx.x;
  int b = bid / TOPK, i = bid - b * TOPK;
  int j = threadIdx.x;
  const float4* OB = (const float4*)topOB + (size_t)b * TOPKP;
  float4 A = OB[i];
  float aw = fmaxf(A.z - A.x, 0.f), ah = fmaxf(A.w - A.y, 0.f);
  float areaA = aw * ah;
  bool bit = false;
  if (j > i && j < TOPK) {
    float4 Bx = OB[j];
    float bw = fmaxf(Bx.z - Bx.x, 0.f), bh = fmaxf(Bx.w - Bx.y, 0.f);
    float areaB = bw * bh;
    float ix1 = fmaxf(A.x, Bx.x), iy1 = fmaxf(A.y, Bx.y);
    float ix2 = fminf(A.z, Bx.z), iy2 = fminf(A.w, Bx.w);
    float inter = fmaxf(ix2 - ix1, 0.f) * fmaxf(iy2 - iy1, 0.f);
    float uni = areaA + areaB - inter;
    float iou = inter / fmaxf(uni, 1e-9f);
    bit = iou > IOU_THR;
  }
  ull m = __ballot(bit ? 1 : 0);
  if ((j & 63) == 0) sup[((size_t)b * TOPKP + i) * 16 + (j >> 6)] = m;
}

// ---------------------------------------------------------------- kernel 6 --
// LDS-staged greedy scan, ONE BLOCK (4 waves) per image. R7/R8/R9 all hit the
// same ~45us wall with 3 different chain structures -> the wall is load MLP
// (~272 span loads consumed span-by-span at ~2 in flight, 1 wave). Fix:
// producer/consumer split. Waves 1-3 stage span-group g+1 (2 spans = 16KB)
// into double-buffered LDS with 192 threads x ~11 independent coalesced loads
// (MLP >> latency) while wave 0 processes group g from LDS: diag words are
// side-extracted to dgls during staging (a direct LDS diag read is a 32-way
// bank conflict); the 64-step serial scan is R9's register-only readlane
// scalar chain; phase B ORs kept rows from LDS (16 pipelined ds_reads).
#define CS(K) { unsigned rl = __builtin_amdgcn_readlane(dlo, (K));             \
    unsigned rh = __builtin_amdgcn_readlane(dhi, (K));                         \
    ull take = (M >> (K)) & 1ull; ull msk = 0ull - take;                       \
    M &= ~((((ull)rh << 32) | (ull)rl) & msk); km |= take << (K); }
#define CS8(B8) CS((B8)+0) CS((B8)+1) CS((B8)+2) CS((B8)+3) CS((B8)+4)         \
    CS((B8)+5) CS((B8)+6) CS((B8)+7)

__global__ __launch_bounds__(256) void nms_scan_kernel(const ull* __restrict__ sup,
    const ull* __restrict__ validWords, const float* __restrict__ topS,
    const int* __restrict__ topL, float* __restrict__ out) {
  __shared__ ull ls[2][2048];     // 2 x 16KB span-group buffers (2 spans each)
  __shared__ ull dgls[2][128];    // per-group diag words (row-local)
  int b = blockIdx.x, tid = threadIdx.x;
  int wave = tid >> 6, lane = tid & 63;
  const ull* S = sup + (size_t)b * TOPKP * 16;

  // prologue: all 256 threads stage group 0 (spans 0,1 = rows 0..127)
  for (int k = 0; k < 8; ++k) {
    int j = tid + 256 * k;              // 0..2047, coalesced
    ull v = S[j];
    ls[0][j] = v;
    // diag: row r=j>>4 (global row, g=0), span = r>>6 = j>>10, word j&15
    if ((j & 15) == (j >> 10)) dgls[0][j >> 4] = v;
  }
  ull rm = 0xFFFFFFFFFFFFFFFFull;
  if (wave == 0 && lane < 16) rm = ~validWords[b * 16 + lane];
  __syncthreads();

  for (int g = 0; g < 8; ++g) {
    if (wave > 0 && g < 7) {            // waves 1-3: stage group g+1
      const ull* src = S + (size_t)(g + 1) * 2048;
      ull* dst = ls[(g + 1) & 1];
      ull* ddst = dgls[(g + 1) & 1];
      int base = 2 * (g + 1);           // first span of the staged group
      for (int j = tid - 64; j < 2048; j += 192) {
        ull v = src[j];
        dst[j] = v;
        if ((j & 15) == base + (j >> 10)) ddst[j >> 4] = v;
      }
    }
    if (wave == 0) {                    // wave 0: process group g from LDS
      const ull* B = ls[g & 1];
      const ull* D = dgls[g & 1];
      int lg = lane >> 4, wd = lane & 15;
      for (int wl = 0; wl < 2; ++wl) {
        int w = 2 * g + wl;
        ull dg = D[wl * 64 + lane];     // diag word of row w*64+lane
        unsigned dlo = (unsigned)dg, dhi = (unsigned)(dg >> 32);
        unsigned mlo = __builtin_amdgcn_readlane((unsigned)rm, w);
        unsigned mhi = __builtin_amdgcn_readlane((unsigned)(rm >> 32), w);
        ull M = ~(((ull)mhi << 32) | (ull)mlo);   // alive mask of span w
        ull km = 0;
        CS8(0) CS8(8) CS8(16) CS8(24) CS8(32) CS8(40) CS8(48) CS8(56)
        // phase B: lane (lg,wd) ORs rows lg+4t word wd under kept mask
        const ull* RB = B + (size_t)(wl * 64 + lg) * 16 + wd;
        ull accB = 0;
#pragma unroll
        for (int t = 0; t < 16; ++t) {
          ull bit = (km >> (4 * t + lg)) & 1ull;
          accB |= RB[(size_t)t * 64] & (0ull - bit);
        }
        accB |= __shfl_xor(accB, 16);
        accB |= __shfl_xor(accB, 32);   // fold 4 lane groups
        rm |= accB;
      }
    }
    __syncthreads();
  }

  if (wave == 0) {
    ull keep_na = ~rm;   // lanes 0..15: keep word lane
    const float* tS = topS + (size_t)b * TOPKP;
    const int*   tL = topL + (size_t)b * TOPKP;
    float* outS = out;                          // [16,1000]
    float* outL = out + BATCH * TOPK;           // [16,1000] labels as float
    float* outK = out + BATCH * TOPK * 6;       // after boxes block
    for (int t = 0; t < 16; ++t) {
      int j = t * 64 + lane;
      ull kw = __shfl(keep_na, t);
      if (j < TOPK) {
        bool kp = (kw >> lane) & 1ull;
        outS[(size_t)b * TOPK + j] = kp ? tS[j] : 0.f;
        outL[(size_t)b * TOPK + j] = kp ? (float)tL[j] : 0.f;
        outK[(size_t)b * TOPK + j] = kp ? 1.f : 0.f;
      }
    }
  }
}
#undef CS8
#undef CS

// -------------------------------------------------------------------- host --
extern "C" void kernel_launch(void* const* d_in, const int* in_sizes, int n_in,
                              void* d_out, int out_size, void* d_ws, size_t ws_size,
                              hipStream_t stream) {
  Ptrs p;
  for (int l = 0; l < 5; ++l) {
    p.cls[l] = (const float*)d_in[l];
    p.reg[l] = (const float*)d_in[5 + l];
    p.ctr[l] = (const float*)d_in[10 + l];
  }
  char* ws = (char*)d_ws;
  size_t o = 0;
  auto alloc = [&](size_t bytes) -> void* {
    void* r = ws + o; o += (bytes + 255) & ~(size_t)255; return r;
  };
  ull*   keys       = (ull*)  alloc((size_t)BATCH * NPAD * 8);
  int*   labels     = (int*)  alloc((size_t)BATCH * NLOC * 4);
  float* boxes      = (float*)alloc((size_t)BATCH * NLOC * 16);
  ull*   runs       = (ull*)  alloc((size_t)BATCH * NCHUNK * TOPKP * 8);
  ull*   runs2      = (ull*)  alloc((size_t)BATCH * NCHUNK * TOPKP * 8);
  ull*   topkeys    = (ull*)  alloc((size_t)BATCH * TOPKP * 8);
  float* topS       = (float*)alloc((size_t)BATCH * TOPKP * 4);
  int*   topL       = (int*)  alloc((size_t)BATCH * TOPKP * 4);
  float* topOB      = (float*)alloc((size_t)BATCH * TOPKP * 16);
  ull*   validWords = (ull*)  alloc((size_t)BATCH * 16 * 8);
  ull*   sup        = (ull*)  alloc((size_t)BATCH * TOPKP * 16 * 8);

  float* out = (float*)d_out;
  float* outBoxes = out + 2 * BATCH * TOPK;   // offset 32000

  hipLaunchKernelGGL(score_kernel, dim3((BATCH * NPAD + 255) / 256), dim3(256), 0, stream,
                     p, keys, labels, boxes);
  hipLaunchKernelGGL(chunk_sort_kernel, dim3(BATCH * NCHUNK), dim3(512), 0, stream,
                     keys, runs);
  // tree merge: 9 -> 5 -> 3 -> 2 -> 1 (ping-pong runs/runs2)
  hipLaunchKernelGGL(merge_level_kernel, dim3(BATCH * 5), dim3(512), 0, stream,
                     runs, runs2, 4, 1, NCHUNK, NCHUNK);
  hipLaunchKernelGGL(merge_level_kernel, dim3(BATCH * 3), dim3(512), 0, stream,
                     runs2, runs, 2, 1, NCHUNK, NCHUNK);
  hipLaunchKernelGGL(merge_level_kernel, dim3(BATCH * 2), dim3(512), 0, stream,
                     runs, runs2, 1, 1, NCHUNK, NCHUNK);
  hipLaunchKernelGGL(merge_level_kernel, dim3(BATCH * 1), dim3(512), 0, stream,
                     runs2, topkeys, 1, 0, NCHUNK, 1);
  hipLaunchKernelGGL(gather_kernel, dim3(BATCH), dim3(256), 0, stream,
                     topkeys, labels, boxes, topS, topL, topOB, validWords, outBoxes);
  hipLaunchKernelGGL(sup_kernel, dim3(BATCH * TOPK), dim3(1024), 0, stream,
                     topOB, sup);
  hipLaunchKernelGGL(nms_scan_kernel, dim3(BATCH), dim3(256), 0, stream,
                     sup, validWords, topS, topL, out);
}

// Round 11
// 253.526 us; speedup vs baseline: 1.0076x; 1.0033x over previous
//
#include <hip/hip_runtime.h>
#include <cstdint>

// FCOS detection post-process for MI355X.
// Pipeline: score/box decode -> per-image exact top-1000 (bitonic chunk sort +
// tree merge) -> suppression bitmask -> LDS-staged greedy NMS scan -> outputs.

typedef unsigned long long ull;

#define BATCH 16
#define NLOC 17064      // total FPN locations per image
#define NPAD 18432      // padded to 9 * 2048
#define NCHUNK 9
#define CHUNK 2048
#define TOPK 1000
#define TOPKP 1024
#define NCLS 80
#define SCORE_THR 0.05f
#define IOU_THR 0.6f

struct Ptrs { const float* cls[5]; const float* reg[5]; const float* ctr[5]; };

// ---------------------------------------------------------------- kernel 1 --
// One thread per (image, location): argmax over 80 class logits (sigmoid is
// monotonic), score = sqrt(sig(cls_max)*sig(ctr)), box decode, pack sort key.
// Key = (score_bits << 32) | (0xFFFFFFFF - n): descending sort == lax.top_k
// order (ties -> smaller index first). Padding locations get key 0.
__global__ __launch_bounds__(256) void score_kernel(Ptrs p, ull* __restrict__ keys,
                                                    int* __restrict__ labels,
                                                    float* __restrict__ boxes) {
  int idx = blockIdx.x * 256 + threadIdx.x;
  if (idx >= BATCH * NPAD) return;
  int b = idx / NPAD, n = idx - b * NPAD;
  if (n >= NLOC) { keys[idx] = 0ull; return; }

  int lvl, off, lw, st, H;
  if (n < 12800)      { lvl=0; off=0;     lw=7; st=8;   H=100; }
  else if (n < 16000) { lvl=1; off=12800; lw=6; st=16;  H=50;  }
  else if (n < 16800) { lvl=2; off=16000; lw=5; st=32;  H=25;  }
  else if (n < 17008) { lvl=3; off=16800; lw=4; st=64;  H=13;  }
  else                { lvl=4; off=17008; lw=3; st=128; H=7;   }
  int hw = n - off;
  int w = hw & ((1 << lw) - 1), h = hw >> lw;
  int HW = H << lw;
  float fs = (float)st, half = fs * 0.5f;
  float x = (float)w * fs + half, y = (float)h * fs + half;

  // coalesced across threads (consecutive hw) for each class c
  const float* cb = p.cls[lvl] + (size_t)b * NCLS * HW + hw;
  float best = cb[0]; int bi = 0;
  for (int c = 1; c < NCLS; ++c) {
    float v = cb[(size_t)c * HW];
    if (v > best) { best = v; bi = c; }   // strict > keeps first max (jnp.argmax)
  }
  const float* rb = p.reg[lvl] + (size_t)b * 4 * HW + hw;
  float r0 = rb[0], r1 = rb[HW], r2 = rb[2 * (size_t)HW], r3 = rb[3 * (size_t)HW];
  float ct = p.ctr[lvl][(size_t)b * HW + hw];

  float pcls = 1.f / (1.f + expf(-best));
  float pctr = 1.f / (1.f + expf(-ct));
  float score = sqrtf(pcls * pctr);   // (0,1), always positive -> monotonic bits

  keys[idx] = ((ull)__float_as_uint(score) << 32) | (ull)(0xFFFFFFFFu - (unsigned)n);
  labels[(size_t)b * NLOC + n] = bi + 1;
  float* bx = boxes + ((size_t)b * NLOC + n) * 4;
  bx[0] = x - r0; bx[1] = y - r1; bx[2] = x + r2; bx[3] = y + r3;
}

// ---------------------------------------------------------------- kernel 2 --
// Bitonic sort of one 2048 chunk in LDS (descending); emit top-1024.
__global__ __launch_bounds__(512) void chunk_sort_kernel(const ull* __restrict__ keys,
                                                         ull* __restrict__ runs) {
  __shared__ ull s[CHUNK];
  int b = blockIdx.x / NCHUNK, c = blockIdx.x % NCHUNK;
  const ull* src = keys + (size_t)b * NPAD + (size_t)c * CHUNK;
  for (int i = threadIdx.x; i < CHUNK; i += 512) s[i] = src[i];
  __syncthreads();
  for (int k = 2; k <= CHUNK; k <<= 1) {
    for (int j = k >> 1; j > 0; j >>= 1) {
      for (int t = threadIdx.x; t < CHUNK / 2; t += 512) {
        int i = ((t & ~(j - 1)) << 1) | (t & (j - 1));
        int ixj = i | j;
        bool desc = (i & k) == 0;
        ull a = s[i], bb = s[ixj];
        bool sw = desc ? (a < bb) : (a > bb);
        if (sw) { s[i] = bb; s[ixj] = a; }
      }
      __syncthreads();
    }
  }
  ull* dst = runs + ((size_t)b * NCHUNK + c) * TOPKP;
  for (int i = threadIdx.x; i < TOPKP; i += 512) dst[i] = s[i];
}

// ---------------------------------------------------------------- kernel 3 --
// One tree-merge level: block (b,p) merges src runs (2p,2p+1) -> dst run p,
// keeping only the top-1024 (first bitonic-merge pass + descending clean of
// the top half). Carry block copies the odd run through. Ping-pong buffers.
__global__ __launch_bounds__(512) void merge_level_kernel(const ull* __restrict__ src,
    ull* __restrict__ dst, int npairs, int carry, int srcRPI, int dstRPI) {
  int per = npairs + carry;
  int b = blockIdx.x / per, p = blockIdx.x % per;
  const ull* sb = src + (size_t)b * srcRPI * TOPKP;
  ull* db = dst + (size_t)b * dstRPI * TOPKP;
  int tid = threadIdx.x;
  if (p >= npairs) {   // carry: copy last odd run through
    for (int i = tid; i < TOPKP; i += 512)
      db[(size_t)p * TOPKP + i] = sb[(size_t)(2 * npairs) * TOPKP + i];
    return;
  }
  __shared__ ull m[TOPKP];
  const ull* A = sb + (size_t)(2 * p) * TOPKP;
  const ull* B = sb + (size_t)(2 * p + 1) * TOPKP;
  // pass j=1024 of the 2048 bitonic merge: top half = max(A[i], B[1023-i])
  for (int i = tid; i < TOPKP; i += 512) {
    ull a = A[i], c = B[TOPKP - 1 - i];
    m[i] = a > c ? a : c;
  }
  __syncthreads();
  // descending bitonic clean of the (bitonic) top half
  for (int j = TOPKP / 2; j > 0; j >>= 1) {
    for (int t = tid; t < TOPKP / 2; t += 512) {
      int i = ((t & ~(j - 1)) << 1) | (t & (j - 1));
      int ixj = i | j;
      ull a = m[i], c = m[ixj];
      if (a < c) { m[i] = c; m[ixj] = a; }
    }
    __syncthreads();
  }
  for (int i = tid; i < TOPKP; i += 512) db[(size_t)p * TOPKP + i] = m[i];
}

// ---------------------------------------------------------------- kernel 4 --
// Decode keys, gather label/box, write output boxes, coord_max reduction
// (exact: max is order-independent), class-offset boxes, valid-bit words.
__global__ __launch_bounds__(256) void gather_kernel(const ull* __restrict__ topkeys,
    const int* __restrict__ labels, const float* __restrict__ boxes,
    float* __restrict__ topS, int* __restrict__ topL, float* __restrict__ topOB,
    ull* __restrict__ validWords, float* __restrict__ outBoxes) {
  __shared__ float red[256];
  __shared__ float s_cmax;
  int b = blockIdx.x, tid = threadIdx.x;
  float lmax = 0.f;   // reference maxes over where(valid, bx, 0) -> zeros included
  for (int k = tid; k < TOPKP; k += 256) {
    ull key = topkeys[(size_t)b * TOPKP + k];
    float sc = 0.f; int lb = 0;
    float b0 = 0.f, b1 = 0.f, b2 = 0.f, b3 = 0.f;
    bool inR = (k < TOPK);
    if (inR) {
      sc = __uint_as_float((unsigned)(key >> 32));
      unsigned n = 0xFFFFFFFFu - (unsigned)(key & 0xFFFFFFFFull);
      lb = labels[(size_t)b * NLOC + n];
      const float* bp = boxes + ((size_t)b * NLOC + n) * 4;
      b0 = bp[0]; b1 = bp[1]; b2 = bp[2]; b3 = bp[3];
      float* ob = outBoxes + ((size_t)b * TOPK + k) * 4;
      ob[0] = b0; ob[1] = b1; ob[2] = b2; ob[3] = b3;   // boxes output: all 1000
    }
    topS[(size_t)b * TOPKP + k] = sc;
    topL[(size_t)b * TOPKP + k] = lb;
    float* tb = topOB + ((size_t)b * TOPKP + k) * 4;
    tb[0] = b0; tb[1] = b1; tb[2] = b2; tb[3] = b3;
    bool valid = inR && (sc > SCORE_THR);
    if (valid) lmax = fmaxf(lmax, fmaxf(fmaxf(b0, b1), fmaxf(b2, b3)));
    ull vb = __ballot(valid ? 1 : 0);
    if ((tid & 63) == 0) validWords[b * 16 + (k >> 6)] = vb;
  }
  red[tid] = lmax;
  __syncthreads();
  for (int sft = 128; sft > 0; sft >>= 1) {
    if (tid < sft) red[tid] = fmaxf(red[tid], red[tid + sft]);
    __syncthreads();
  }
  if (tid == 0) s_cmax = red[0];
  __syncthreads();
  float offb = s_cmax + 1.0f;
  for (int k = tid; k < TOPKP; k += 256) {
    float off = (float)topL[(size_t)b * TOPKP + k] * offb;   // class-offset trick
    float* tb = topOB + ((size_t)b * TOPKP + k) * 4;
    tb[0] += off; tb[1] += off; tb[2] += off; tb[3] += off;
  }
}

// ---------------------------------------------------------------- kernel 5 --
// Suppression bitmask: block (b,i), thread j: bit = (j>i) & (iou(i,j) > thr).
// 16 uint64 words per row via per-wave ballot. Row stride = 16 words; rows
// stored at (b*TOPKP + i). FP op order mirrors reference.
__global__ __launch_bounds__(1024) void sup_kernel(const float* __restrict__ topOB,
                                                   ull* __restrict__ sup) {
  int bid = blockIdx.x;
  int b = bid / TOPK, i = bid - b * TOPK;
  int j = threadIdx.x;
  const float4* OB = (const float4*)topOB + (size_t)b * TOPKP;
  float4 A = OB[i];
  float aw = fmaxf(A.z - A.x, 0.f), ah = fmaxf(A.w - A.y, 0.f);
  float areaA = aw * ah;
  bool bit = false;
  if (j > i && j < TOPK) {
    float4 Bx = OB[j];
    float bw = fmaxf(Bx.z - Bx.x, 0.f), bh = fmaxf(Bx.w - Bx.y, 0.f);
    float areaB = bw * bh;
    float ix1 = fmaxf(A.x, Bx.x), iy1 = fmaxf(A.y, Bx.y);
    float ix2 = fminf(A.z, Bx.z), iy2 = fminf(A.w, Bx.w);
    float inter = fmaxf(ix2 - ix1, 0.f) * fmaxf(iy2 - iy1, 0.f);
    float uni = areaA + areaB - inter;
    float iou = inter / fmaxf(uni, 1e-9f);
    bit = iou > IOU_THR;
  }
  ull m = __ballot(bit ? 1 : 0);
  if ((j & 63) == 0) sup[((size_t)b * TOPKP + i) * 16 + (j >> 6)] = m;
}

// ---------------------------------------------------------------- kernel 6 --
// LDS-staged greedy scan, one 256-thread block per image, T14 issue-early/
// write-late staging. R7-R10 all pinned at ~45us = load-MLP wall: R10's
// staging loop had a per-iteration load->ds_write dependency through ONE
// register -> vmcnt(0) per iteration -> MLP=1 -> ~10k cyc/group staging on
// the critical path (matches 45us quantitatively). Fix: each thread loads its
// 8 next-group values into 8 NAMED registers back-to-back (2048 loads in
// flight block-wide, single vmcnt wait), sched_barrier(0) pins the issue,
// wave 0 computes group g from LDS (VALU+DS only -> loads stay in flight),
// THEN all threads write the regs to the other LDS buffer (vmcnt already
// satisfied by then). Chain = R9's register-only readlane scalar chain.
// Diag read straight from LDS (64-way conflict, once per span ~ 100cyc).
#define CS(K) { unsigned rl = __builtin_amdgcn_readlane(dlo, (K));             \
    unsigned rh = __builtin_amdgcn_readlane(dhi, (K));                         \
    ull take = (M >> (K)) & 1ull; ull msk = 0ull - take;                       \
    M &= ~((((ull)rh << 32) | (ull)rl) & msk); km |= take << (K); }
#define CS8(B8) CS((B8)+0) CS((B8)+1) CS((B8)+2) CS((B8)+3) CS((B8)+4)         \
    CS((B8)+5) CS((B8)+6) CS((B8)+7)

__global__ __launch_bounds__(256) void nms_scan_kernel(const ull* __restrict__ sup,
    const ull* __restrict__ validWords, const float* __restrict__ topS,
    const int* __restrict__ topL, float* __restrict__ out) {
  __shared__ ull ls[2][2048];     // 2 x 16KB span-group buffers (2 spans each)
  int b = blockIdx.x, tid = threadIdx.x;
  int wave = tid >> 6, lane = tid & 63;
  const ull* S = sup + (size_t)b * TOPKP * 16;

  ull rm = 0xFFFFFFFFFFFFFFFFull;
  if (wave == 0 && lane < 16) rm = ~validWords[b * 16 + lane];

  // prologue: stage group 0, reg-batched (8 loads issued, then 8 writes)
  {
    ull s0 = S[tid], s1 = S[tid + 256], s2 = S[tid + 512], s3 = S[tid + 768],
        s4 = S[tid + 1024], s5 = S[tid + 1280], s6 = S[tid + 1536],
        s7 = S[tid + 1792];
    ls[0][tid] = s0;        ls[0][tid + 256] = s1;  ls[0][tid + 512] = s2;
    ls[0][tid + 768] = s3;  ls[0][tid + 1024] = s4; ls[0][tid + 1280] = s5;
    ls[0][tid + 1536] = s6; ls[0][tid + 1792] = s7;
  }
  __syncthreads();

  for (int g = 0; g < 8; ++g) {
    // issue next-group loads into named regs (no consumer until write phase)
    ull s0 = 0, s1 = 0, s2 = 0, s3 = 0, s4 = 0, s5 = 0, s6 = 0, s7 = 0;
    bool st = (g < 7);
    if (st) {
      const ull* src = S + (size_t)(g + 1) * 2048;
      s0 = src[tid];        s1 = src[tid + 256];  s2 = src[tid + 512];
      s3 = src[tid + 768];  s4 = src[tid + 1024]; s5 = src[tid + 1280];
      s6 = src[tid + 1536]; s7 = src[tid + 1792];
    }
    __builtin_amdgcn_sched_barrier(0);   // pin load issue before compute

    if (wave == 0) {                     // wave 0: process group g from LDS
      const ull* Bf = ls[g & 1];
      int lg = lane >> 4, wd = lane & 15;
      for (int wl = 0; wl < 2; ++wl) {
        int w = 2 * g + wl;
        ull dg = Bf[(size_t)(wl * 64 + lane) * 16 + w];   // diag of row w*64+lane
        unsigned dlo = (unsigned)dg, dhi = (unsigned)(dg >> 32);
        unsigned mlo = __builtin_amdgcn_readlane((unsigned)rm, w);
        unsigned mhi = __builtin_amdgcn_readlane((unsigned)(rm >> 32), w);
        ull M = ~(((ull)mhi << 32) | (ull)mlo);   // alive mask of span w
        ull km = 0;
        CS8(0) CS8(8) CS8(16) CS8(24) CS8(32) CS8(40) CS8(48) CS8(56)
        // phase B: lane (lg,wd) ORs rows lg+4t word wd under kept mask
        const ull* RB = Bf + (size_t)(wl * 64 + lg) * 16 + wd;
        ull accB = 0;
#pragma unroll
        for (int t = 0; t < 16; ++t) {
          ull bit = (km >> (4 * t + lg)) & 1ull;
          accB |= RB[(size_t)t * 64] & (0ull - bit);
        }
        accB |= __shfl_xor(accB, 16);
        accB |= __shfl_xor(accB, 32);   // fold 4 lane groups
        rm |= accB;
      }
    }

    if (st) {                            // write-late: vmcnt satisfied by now
      ull* dst = ls[(g + 1) & 1];
      dst[tid] = s0;        dst[tid + 256] = s1;  dst[tid + 512] = s2;
      dst[tid + 768] = s3;  dst[tid + 1024] = s4; dst[tid + 1280] = s5;
      dst[tid + 1536] = s6; dst[tid + 1792] = s7;
    }
    __syncthreads();
  }

  if (wave == 0) {
    ull keep_na = ~rm;   // lanes 0..15: keep word lane
    const float* tS = topS + (size_t)b * TOPKP;
    const int*   tL = topL + (size_t)b * TOPKP;
    float* outS = out;                          // [16,1000]
    float* outL = out + BATCH * TOPK;           // [16,1000] labels as float
    float* outK = out + BATCH * TOPK * 6;       // after boxes block
    for (int t = 0; t < 16; ++t) {
      int j = t * 64 + lane;
      ull kw = __shfl(keep_na, t);
      if (j < TOPK) {
        bool kp = (kw >> lane) & 1ull;
        outS[(size_t)b * TOPK + j] = kp ? tS[j] : 0.f;
        outL[(size_t)b * TOPK + j] = kp ? (float)tL[j] : 0.f;
        outK[(size_t)b * TOPK + j] = kp ? 1.f : 0.f;
      }
    }
  }
}
#undef CS8
#undef CS

// -------------------------------------------------------------------- host --
extern "C" void kernel_launch(void* const* d_in, const int* in_sizes, int n_in,
                              void* d_out, int out_size, void* d_ws, size_t ws_size,
                              hipStream_t stream) {
  Ptrs p;
  for (int l = 0; l < 5; ++l) {
    p.cls[l] = (const float*)d_in[l];
    p.reg[l] = (const float*)d_in[5 + l];
    p.ctr[l] = (const float*)d_in[10 + l];
  }
  char* ws = (char*)d_ws;
  size_t o = 0;
  auto alloc = [&](size_t bytes) -> void* {
    void* r = ws + o; o += (bytes + 255) & ~(size_t)255; return r;
  };
  ull*   keys       = (ull*)  alloc((size_t)BATCH * NPAD * 8);
  int*   labels     = (int*)  alloc((size_t)BATCH * NLOC * 4);
  float* boxes      = (float*)alloc((size_t)BATCH * NLOC * 16);
  ull*   runs       = (ull*)  alloc((size_t)BATCH * NCHUNK * TOPKP * 8);
  ull*   runs2      = (ull*)  alloc((size_t)BATCH * NCHUNK * TOPKP * 8);
  ull*   topkeys    = (ull*)  alloc((size_t)BATCH * TOPKP * 8);
  float* topS       = (float*)alloc((size_t)BATCH * TOPKP * 4);
  int*   topL       = (int*)  alloc((size_t)BATCH * TOPKP * 4);
  float* topOB      = (float*)alloc((size_t)BATCH * TOPKP * 16);
  ull*   validWords = (ull*)  alloc((size_t)BATCH * 16 * 8);
  ull*   sup        = (ull*)  alloc((size_t)BATCH * TOPKP * 16 * 8);

  float* out = (float*)d_out;
  float* outBoxes = out + 2 * BATCH * TOPK;   // offset 32000

  hipLaunchKernelGGL(score_kernel, dim3((BATCH * NPAD + 255) / 256), dim3(256), 0, stream,
                     p, keys, labels, boxes);
  hipLaunchKernelGGL(chunk_sort_kernel, dim3(BATCH * NCHUNK), dim3(512), 0, stream,
                     keys, runs);
  // tree merge: 9 -> 5 -> 3 -> 2 -> 1 (ping-pong runs/runs2)
  hipLaunchKernelGGL(merge_level_kernel, dim3(BATCH * 5), dim3(512), 0, stream,
                     runs, runs2, 4, 1, NCHUNK, NCHUNK);
  hipLaunchKernelGGL(merge_level_kernel, dim3(BATCH * 3), dim3(512), 0, stream,
                     runs2, runs, 2, 1, NCHUNK, NCHUNK);
  hipLaunchKernelGGL(merge_level_kernel, dim3(BATCH * 2), dim3(512), 0, stream,
                     runs, runs2, 1, 1, NCHUNK, NCHUNK);
  hipLaunchKernelGGL(merge_level_kernel, dim3(BATCH * 1), dim3(512), 0, stream,
                     runs2, topkeys, 1, 0, NCHUNK, 1);
  hipLaunchKernelGGL(gather_kernel, dim3(BATCH), dim3(256), 0, stream,
                     topkeys, labels, boxes, topS, topL, topOB, validWords, outBoxes);
  hipLaunchKernelGGL(sup_kernel, dim3(BATCH * TOPK), dim3(1024), 0, stream,
                     topOB, sup);
  hipLaunchKernelGGL(nms_scan_kernel, dim3(BATCH), dim3(256), 0, stream,
                     sup, validWords, topS, topL, out);
}